// Round 1
// baseline (581.446 us; speedup 1.0000x reference)
//
#include <hip/hip_runtime.h>
#include <stdint.h>

// Problem constants: B=8, N=4096, C=768, H=8, hd=96
// FLOP budget: GEMM1 116G + attn 9.7G + GEMM3 38.7G. bf16 MFMA path.

typedef __attribute__((ext_vector_type(8))) __bf16 bf16x8;
typedef __attribute__((ext_vector_type(4))) float f32x4;

__device__ __forceinline__ unsigned short f2b(float f) {
  uint32_t u = __float_as_uint(f);
  u += 0x7FFF + ((u >> 16) & 1);          // round-to-nearest-even
  return (unsigned short)(u >> 16);
}
__device__ __forceinline__ float b2f(unsigned short h) {
  return __uint_as_float(((uint32_t)h) << 16);
}

// async global->LDS, 16B/lane. LDS dst must be wave-uniform base; HW adds lane*16.
__device__ __forceinline__ void gload16(const void* g, void* l) {
  __builtin_amdgcn_global_load_lds(
      (__attribute__((address_space(1))) void*)(uintptr_t)g,
      (__attribute__((address_space(3))) void*)(uintptr_t)l, 16, 0, 0);
}

// ---------------- conversions ----------------
__global__ void cvt_bf16(const float* __restrict__ in, unsigned short* __restrict__ out, int n4) {
  int stride = gridDim.x * blockDim.x;
  for (int i = blockIdx.x * blockDim.x + threadIdx.x; i < n4; i += stride) {
    float4 v = reinterpret_cast<const float4*>(in)[i];
    ushort4 o;
    o.x = f2b(v.x); o.y = f2b(v.y); o.z = f2b(v.z); o.w = f2b(v.w);
    reinterpret_cast<ushort4*>(out)[i] = o;
  }
}

// out[NC][K] = bf16(in[K][NC]^T)  (BT layout for MFMA B operand)
__global__ void cvt_transpose(const float* __restrict__ in, unsigned short* __restrict__ out,
                              int K, int NC) {
  __shared__ float tile[32][33];
  int bx = blockIdx.x;          // NC/32
  int by = blockIdx.y;          // K/32
  int tx = threadIdx.x & 31;
  int ty = threadIdx.x >> 5;    // 0..7
  for (int r = ty; r < 32; r += 8)
    tile[r][tx] = in[(size_t)(by * 32 + r) * NC + bx * 32 + tx];
  __syncthreads();
  for (int r = ty; r < 32; r += 8)
    out[(size_t)(bx * 32 + r) * K + by * 32 + tx] = f2b(tile[tx][r]);
}

// ---------------- GEMM1: qkv = x @ Wqkv, scattered to q/k [d][n] and v [n][e] ----------------
// A = xb [32768][768] bf16 row-major; Bt = WqkvT [2304][768] bf16.
// qkT layout: [2][64 bh][96 d][4096 n]; vT layout: [64 bh][4096 n][96 e].
__global__ __launch_bounds__(256, 2) void gemm_qkv(
    const unsigned short* __restrict__ A, const unsigned short* __restrict__ Bt,
    unsigned short* __restrict__ qkT, unsigned short* __restrict__ vT) {
  __shared__ unsigned short lds[16384];       // As [128][32] @0, Bs [128][32] @4096; bounce uses all 32KB
  int bj = blockIdx.x;                        // 0..17
  int bm = blockIdx.y;                        // 0..255
  int m0 = bm * 128, j0 = bj * 128;
  int tid = threadIdx.x;
  int wid = tid >> 6, lane = tid & 63;
  int wm = wid >> 1, wn = wid & 1;
  int quad = lane >> 4, l16 = lane & 15;
  int srow = lane >> 2, sch = lane & 3;       // staging: 16 rows/wave, 4x16B chunks/row

  f32x4 acc[4][4];
  f32x4 z = {0.f, 0.f, 0.f, 0.f};
#pragma unroll
  for (int i = 0; i < 4; i++)
#pragma unroll
    for (int j = 0; j < 4; j++) acc[i][j] = z;

  const unsigned short* Ab = A + (size_t)m0 * 768;
  const unsigned short* Bb = Bt + (size_t)j0 * 768;

  for (int k0 = 0; k0 < 768; k0 += 32) {
#pragma unroll
    for (int i = 0; i < 2; i++) {
      int r = i * 64 + wid * 16 + srow;
      gload16(Ab + (size_t)r * 768 + k0 + sch * 8, &lds[(i * 64 + wid * 16) * 32]);
      gload16(Bb + (size_t)r * 768 + k0 + sch * 8, &lds[4096 + (i * 64 + wid * 16) * 32]);
    }
    __syncthreads();
    bf16x8 af[4], bfr[4];
#pragma unroll
    for (int mi = 0; mi < 4; mi++)
      af[mi] = *(const bf16x8*)&lds[(wm * 64 + mi * 16 + l16) * 32 + quad * 8];
#pragma unroll
    for (int ni = 0; ni < 4; ni++)
      bfr[ni] = *(const bf16x8*)&lds[4096 + (wn * 64 + ni * 16 + l16) * 32 + quad * 8];
#pragma unroll
    for (int mi = 0; mi < 4; mi++)
#pragma unroll
      for (int ni = 0; ni < 4; ni++)
        acc[mi][ni] = __builtin_amdgcn_mfma_f32_16x16x32_bf16(af[mi], bfr[ni], acc[mi][ni], 0, 0, 0);
    __syncthreads();
  }

  // epilogue: bounce tile through LDS so global writes are 16B-contiguous
  int s = bj / 6;                  // 0=q,1=k,2=v (tiles never straddle s: 2304 = 3*768, 768 = 6*128)
  int b = bm >> 5;                 // token-block -> batch (4096/128=32 blocks per batch)
  int n0 = m0 & 4095;
  bool isv = (s == 2);
#pragma unroll
  for (int mi = 0; mi < 4; mi++)
#pragma unroll
    for (int ni = 0; ni < 4; ni++)
#pragma unroll
      for (int r = 0; r < 4; r++) {
        int m = wm * 64 + mi * 16 + quad * 4 + r;     // token within tile
        int cc = wn * 64 + ni * 16 + l16;             // j within tile
        unsigned short v = f2b(acc[mi][ni][r]);
        lds[isv ? (m * 128 + cc) : (cc * 128 + m)] = v;
      }
  __syncthreads();
  if (!isv) {
    // q/k: row j -> n contiguous
#pragma unroll
    for (int it = 0; it < 8; it++) {
      int id = tid + it * 256;                       // 128 j x 16 chunks
      int jr = id >> 4, mc = id & 15;
      int j = j0 + jr;
      int hh = (j - s * 768) / 96;
      int d = j - s * 768 - hh * 96;
      size_t off = ((size_t)(s * 64 + b * 8 + hh) * 96 + d) * 4096 + n0 + mc * 8;
      *(uint4*)&qkT[off] = *(const uint4*)&lds[jr * 128 + mc * 8];
    }
  } else {
    // v: row n -> e contiguous
#pragma unroll
    for (int it = 0; it < 8; it++) {
      int id = tid + it * 256;                       // 128 n x 16 chunks
      int mr = id >> 4, ch = id & 15;
      int cp = (j0 - 1536) + ch * 8;                 // [0,768)
      int hh = cp / 96, e = cp - hh * 96;
      size_t off = ((size_t)(b * 8 + hh) * 4096 + (n0 + mr)) * 96 + e;
      *(uint4*)&vT[off] = *(const uint4*)&lds[mr * 128 + ch * 8];
    }
  }
}

// ---------------- norms (and zero S) ----------------
__global__ __launch_bounds__(256) void norms_k(const unsigned short* __restrict__ qkT,
                                               float* __restrict__ invn,  // [2*64*96]
                                               float* __restrict__ S) {   // zeroed here
  int tid = threadIdx.x;
  for (int i = blockIdx.x * 256 + tid; i < 64 * 96 * 96; i += 128 * 256) S[i] = 0.f;
  int blk = blockIdx.x;                                   // 0..127 = sel*64+bh
  const unsigned short* base = qkT + (size_t)blk * 96 * 4096;
  int wid = tid >> 6, lane = tid & 63;
  for (int r = wid; r < 96; r += 4) {
    const unsigned short* p = base + (size_t)r * 4096;
    float ss = 0.f;
#pragma unroll
    for (int i = 0; i < 8; i++) {
      uint4 u = *(const uint4*)&p[lane * 8 + i * 512];
      float a0 = b2f((unsigned short)(u.x & 0xffff)), a1 = b2f((unsigned short)(u.x >> 16));
      float a2 = b2f((unsigned short)(u.y & 0xffff)), a3 = b2f((unsigned short)(u.y >> 16));
      float a4 = b2f((unsigned short)(u.z & 0xffff)), a5 = b2f((unsigned short)(u.z >> 16));
      float a6 = b2f((unsigned short)(u.w & 0xffff)), a7 = b2f((unsigned short)(u.w >> 16));
      ss += a0 * a0 + a1 * a1 + a2 * a2 + a3 * a3 + a4 * a4 + a5 * a5 + a6 * a6 + a7 * a7;
    }
#pragma unroll
    for (int off = 32; off > 0; off >>= 1) ss += __shfl_down(ss, off, 64);
    if (lane == 0) invn[blk * 96 + r] = 1.0f / fmaxf(sqrtf(ss), 1e-12f);
  }
}

// ---------------- split-K S = q @ k^T (raw, unnormalized) ----------------
__global__ __launch_bounds__(256, 2) void attn_s(const unsigned short* __restrict__ qkT,
                                                 float* __restrict__ S) {
  __shared__ unsigned short lds[12288];     // qs [96][64] @0, ks [96][64] @6144
  int blk = blockIdx.x;                     // bh*8 + ksplit
  int bh = blk >> 3, ks = blk & 7;
  const unsigned short* qb = qkT + (size_t)bh * 96 * 4096;
  const unsigned short* kb = qkT + (size_t)(64 + bh) * 96 * 4096;
  int tid = threadIdx.x, wid = tid >> 6, lane = tid & 63;
  int wm = wid >> 1, wn = wid & 1, quad = lane >> 4, l16 = lane & 15;
  int srow = lane >> 3, sch = lane & 7;     // 8 rows/wave, 8x16B chunks per 128B row
  f32x4 acc[3][3];
  f32x4 z = {0.f, 0.f, 0.f, 0.f};
#pragma unroll
  for (int i = 0; i < 3; i++)
#pragma unroll
    for (int j = 0; j < 3; j++) acc[i][j] = z;

  for (int k0 = ks * 512; k0 < ks * 512 + 512; k0 += 64) {
#pragma unroll
    for (int i = 0; i < 3; i++) {
      int r = i * 32 + wid * 8 + srow;
      gload16(qb + (size_t)r * 4096 + k0 + sch * 8, &lds[(i * 32 + wid * 8) * 64]);
      gload16(kb + (size_t)r * 4096 + k0 + sch * 8, &lds[6144 + (i * 32 + wid * 8) * 64]);
    }
    __syncthreads();
#pragma unroll
    for (int kk = 0; kk < 2; kk++) {
      bf16x8 af[3], bfr[3];
#pragma unroll
      for (int mi = 0; mi < 3; mi++)
        af[mi] = *(const bf16x8*)&lds[(wm * 48 + mi * 16 + l16) * 64 + kk * 32 + quad * 8];
#pragma unroll
      for (int ni = 0; ni < 3; ni++)
        bfr[ni] = *(const bf16x8*)&lds[6144 + (wn * 48 + ni * 16 + l16) * 64 + kk * 32 + quad * 8];
#pragma unroll
      for (int mi = 0; mi < 3; mi++)
#pragma unroll
        for (int ni = 0; ni < 3; ni++)
          acc[mi][ni] = __builtin_amdgcn_mfma_f32_16x16x32_bf16(af[mi], bfr[ni], acc[mi][ni], 0, 0, 0);
    }
    __syncthreads();
  }
  float* Sb = S + (size_t)bh * 9216;
#pragma unroll
  for (int mi = 0; mi < 3; mi++)
#pragma unroll
    for (int ni = 0; ni < 3; ni++)
#pragma unroll
      for (int r = 0; r < 4; r++)
        atomicAdd(&Sb[(wm * 48 + mi * 16 + quad * 4 + r) * 96 + wn * 48 + ni * 16 + l16],
                  acc[mi][ni][r]);
}

// ---------------- softmax + out = attn @ v, write U [B][N][C] bf16 ----------------
__global__ __launch_bounds__(256, 2) void attn_v(
    const float* __restrict__ S, const float* __restrict__ invn,
    const float* __restrict__ temp, const unsigned short* __restrict__ vT,
    unsigned short* __restrict__ U) {
  __shared__ unsigned short lds[21504];   // attn [96][96] @0, vs3 [3][128][32] @9216; bounce [128][96] @0
  int blk = blockIdx.x;                   // bh*32 + nchunk
  int bh = blk >> 5, nc = blk & 31;
  int b = bh >> 3, h = bh & 7;
  int n0 = nc * 128;
  int tid = threadIdx.x, wid = tid >> 6, lane = tid & 63;
  int wm = wid >> 1, wn = wid & 1, quad = lane >> 4, l16 = lane & 15;

  // stage v chunk [128 n][96 e] as three [128][32] tiles (async, overlaps softmax)
  const unsigned short* vb = vT + (size_t)bh * 4096 * 96 + (size_t)n0 * 96;
  int srow = lane >> 2, sch = lane & 3;
#pragma unroll
  for (int e = 0; e < 3; e++)
#pragma unroll
    for (int i = 0; i < 2; i++) {
      int r = i * 64 + wid * 16 + srow;
      gload16(vb + (size_t)r * 96 + e * 32 + sch * 8,
              &lds[9216 + e * 4096 + (i * 64 + wid * 16) * 32]);
    }

  // softmax rows (thread d per row); attn = softmax(S * invq_d * invk_e * temp_h)
  if (tid < 96) {
    int d = tid;
    const float* Srow = S + (size_t)bh * 9216 + d * 96;
    const float* ivk = invn + 6144 + bh * 96;
    float iq = invn[bh * 96 + d] * temp[h];
    float mx = -1e30f;
    for (int e = 0; e < 96; e++) mx = fmaxf(mx, Srow[e] * iq * ivk[e]);
    float sum = 0.f;
    for (int e = 0; e < 96; e++) sum += __expf(Srow[e] * iq * ivk[e] - mx);
    float inv = 1.0f / sum;
    for (int e = 0; e < 96; e++)
      lds[d * 96 + e] = f2b(__expf(Srow[e] * iq * ivk[e] - mx) * inv);
  }
  __syncthreads();

  f32x4 acc[3][4];
  f32x4 z = {0.f, 0.f, 0.f, 0.f};
#pragma unroll
  for (int i = 0; i < 3; i++)
#pragma unroll
    for (int j = 0; j < 4; j++) acc[i][j] = z;
#pragma unroll
  for (int et = 0; et < 3; et++) {
    bf16x8 af[3], bfr[4];
#pragma unroll
    for (int mi = 0; mi < 3; mi++)
      af[mi] = *(const bf16x8*)&lds[(wm * 48 + mi * 16 + l16) * 96 + et * 32 + quad * 8];
#pragma unroll
    for (int ni = 0; ni < 4; ni++)
      bfr[ni] = *(const bf16x8*)&lds[9216 + et * 4096 + (wn * 64 + ni * 16 + l16) * 32 + quad * 8];
#pragma unroll
    for (int mi = 0; mi < 3; mi++)
#pragma unroll
      for (int ni = 0; ni < 4; ni++)
        acc[mi][ni] = __builtin_amdgcn_mfma_f32_16x16x32_bf16(af[mi], bfr[ni], acc[mi][ni], 0, 0, 0);
  }
  __syncthreads();

  // bounce out tile as Us[n][d], then coalesced U writes (c-contiguous)
#pragma unroll
  for (int mi = 0; mi < 3; mi++)
#pragma unroll
    for (int ni = 0; ni < 4; ni++)
#pragma unroll
      for (int r = 0; r < 4; r++) {
        int d = wm * 48 + mi * 16 + quad * 4 + r;
        int n = wn * 64 + ni * 16 + l16;
        lds[n * 96 + d] = f2b(acc[mi][ni][r]);
      }
  __syncthreads();
#pragma unroll
  for (int it = 0; it < 6; it++) {
    int id = tid + it * 256;                 // 128 n x 12 chunks of 16B
    int nr = id / 12, ch = id % 12;
    *(uint4*)&U[((size_t)(b * 4096 + n0 + nr)) * 768 + h * 96 + ch * 8] =
        *(const uint4*)&lds[nr * 96 + ch * 8];
  }
}

// ---------------- GEMM3: y = U @ Wproj + bproj (fp32 out) ----------------
__global__ __launch_bounds__(256, 2) void gemm_out(
    const unsigned short* __restrict__ A, const unsigned short* __restrict__ Bt,
    const float* __restrict__ bias, float* __restrict__ out) {
  __shared__ unsigned short lds[8192];
  int bj = blockIdx.x;                     // 0..5
  int bm = blockIdx.y;                     // 0..255
  int m0 = bm * 128, j0 = bj * 128;
  int tid = threadIdx.x;
  int wid = tid >> 6, lane = tid & 63;
  int wm = wid >> 1, wn = wid & 1;
  int quad = lane >> 4, l16 = lane & 15;
  int srow = lane >> 2, sch = lane & 3;

  f32x4 acc[4][4];
  f32x4 z = {0.f, 0.f, 0.f, 0.f};
#pragma unroll
  for (int i = 0; i < 4; i++)
#pragma unroll
    for (int j = 0; j < 4; j++) acc[i][j] = z;

  const unsigned short* Ab = A + (size_t)m0 * 768;
  const unsigned short* Bb = Bt + (size_t)j0 * 768;

  for (int k0 = 0; k0 < 768; k0 += 32) {
#pragma unroll
    for (int i = 0; i < 2; i++) {
      int r = i * 64 + wid * 16 + srow;
      gload16(Ab + (size_t)r * 768 + k0 + sch * 8, &lds[(i * 64 + wid * 16) * 32]);
      gload16(Bb + (size_t)r * 768 + k0 + sch * 8, &lds[4096 + (i * 64 + wid * 16) * 32]);
    }
    __syncthreads();
    bf16x8 af[4], bfr[4];
#pragma unroll
    for (int mi = 0; mi < 4; mi++)
      af[mi] = *(const bf16x8*)&lds[(wm * 64 + mi * 16 + l16) * 32 + quad * 8];
#pragma unroll
    for (int ni = 0; ni < 4; ni++)
      bfr[ni] = *(const bf16x8*)&lds[4096 + (wn * 64 + ni * 16 + l16) * 32 + quad * 8];
#pragma unroll
    for (int mi = 0; mi < 4; mi++)
#pragma unroll
      for (int ni = 0; ni < 4; ni++)
        acc[mi][ni] = __builtin_amdgcn_mfma_f32_16x16x32_bf16(af[mi], bfr[ni], acc[mi][ni], 0, 0, 0);
    __syncthreads();
  }
#pragma unroll
  for (int ni = 0; ni < 4; ni++) {
    int ccol = j0 + wn * 64 + ni * 16 + l16;
    float bv = bias[ccol];
#pragma unroll
    for (int mi = 0; mi < 4; mi++)
#pragma unroll
      for (int r = 0; r < 4; r++)
        out[(size_t)(m0 + wm * 64 + mi * 16 + quad * 4 + r) * 768 + ccol] = acc[mi][ni][r] + bv;
  }
}

// ---------------- host ----------------
extern "C" void kernel_launch(void* const* d_in, const int* in_sizes, int n_in,
                              void* d_out, int out_size, void* d_ws, size_t ws_size,
                              hipStream_t stream) {
  const float* x = (const float*)d_in[0];
  const float* Wqkv = (const float*)d_in[1];
  const float* temp = (const float*)d_in[2];
  const float* Wproj = (const float*)d_in[3];
  const float* bproj = (const float*)d_in[4];
  float* out = (float*)d_out;
  char* ws = (char*)d_ws;

  // workspace layout (bytes); total ~247 MB
  unsigned short* xb     = (unsigned short*)(ws);                 // 50331648
  unsigned short* WqkvT  = (unsigned short*)(ws + 50331648);      // 3538944
  unsigned short* WprojT = (unsigned short*)(ws + 53870592);      // 1179648
  unsigned short* qkT    = (unsigned short*)(ws + 55050240);      // 100663296
  unsigned short* vT     = (unsigned short*)(ws + 155713536);     // 50331648
  unsigned short* U      = (unsigned short*)(ws + 206045184);     // 50331648
  float* S               = (float*)(ws + 256376832);              // 2359296
  float* invn            = (float*)(ws + 258736128);              // 49152

  cvt_bf16<<<dim3(4096), dim3(256), 0, stream>>>(x, xb, 25165824 / 4);
  cvt_transpose<<<dim3(72, 24), dim3(256), 0, stream>>>(Wqkv, WqkvT, 768, 2304);
  cvt_transpose<<<dim3(24, 24), dim3(256), 0, stream>>>(Wproj, WprojT, 768, 768);
  gemm_qkv<<<dim3(18, 256), dim3(256), 0, stream>>>(xb, WqkvT, qkT, vT);
  norms_k<<<dim3(128), dim3(256), 0, stream>>>(qkT, invn, S);
  attn_s<<<dim3(512), dim3(256), 0, stream>>>(qkT, S);
  attn_v<<<dim3(2048), dim3(256), 0, stream>>>(S, invn, temp, vT, U);
  gemm_out<<<dim3(6, 256), dim3(256), 0, stream>>>(U, WprojT, bproj, out);
}

// Round 2
// 479.070 us; speedup vs baseline: 1.2137x; 1.2137x over previous
//
#include <hip/hip_runtime.h>
#include <stdint.h>

// B=8, N=4096, C=768, H=8, hd=96. bf16 MFMA path.
// LDS tiles are row-major [rows][8 chunks of 8 elem] with XOR chunk swizzle:
// LDS slot (row, c) holds global chunk c ^ (row&7)  -> conflict-free ds_read_b128
// while global_load_lds staging stays contiguous (lanes permute within a 128B row).

typedef __attribute__((ext_vector_type(8))) __bf16 bf16x8;
typedef __attribute__((ext_vector_type(4))) float f32x4;

__device__ __forceinline__ unsigned short f2b(float f) {
  uint32_t u = __float_as_uint(f);
  u += 0x7FFF + ((u >> 16) & 1);
  return (unsigned short)(u >> 16);
}

__device__ __forceinline__ void gload16(const void* g, void* l) {
  __builtin_amdgcn_global_load_lds(
      (__attribute__((address_space(1))) void*)(uintptr_t)g,
      (__attribute__((address_space(3))) void*)(uintptr_t)l, 16, 0, 0);
}

// ---------------- conversions + zero S/normsq ----------------
__global__ void cvt_bf16(const float* __restrict__ in, unsigned short* __restrict__ out, int n4,
                         float* __restrict__ Z, int nz4) {
  int gid = blockIdx.x * blockDim.x + threadIdx.x;
  if (gid < nz4) reinterpret_cast<float4*>(Z)[gid] = make_float4(0.f, 0.f, 0.f, 0.f);
  int stride = gridDim.x * blockDim.x;
  for (int i = gid; i < n4; i += stride) {
    float4 v = reinterpret_cast<const float4*>(in)[i];
    ushort4 o;
    o.x = f2b(v.x); o.y = f2b(v.y); o.z = f2b(v.z); o.w = f2b(v.w);
    reinterpret_cast<ushort4*>(out)[i] = o;
  }
}

__global__ void cvt_transpose(const float* __restrict__ in, unsigned short* __restrict__ out,
                              int K, int NC) {
  __shared__ float tile[32][33];
  int bx = blockIdx.x, by = blockIdx.y;
  int tx = threadIdx.x & 31, ty = threadIdx.x >> 5;
  for (int r = ty; r < 32; r += 8)
    tile[r][tx] = in[(size_t)(by * 32 + r) * NC + bx * 32 + tx];
  __syncthreads();
  for (int r = ty; r < 32; r += 8)
    out[(size_t)(bx * 32 + r) * K + by * 32 + tx] = f2b(tile[tx][r]);
}

// ---------------- GEMM1: qkv = x @ Wqkv, scatter + fused norm^2 ----------------
// qkT: [2][64 bh][96 d][4096 n]; vT: [64 bh][4096 n][96 e]; normsq: [2][64][96]
__global__ __launch_bounds__(256, 2) void gemm_qkv(
    const unsigned short* __restrict__ A, const unsigned short* __restrict__ Bt,
    unsigned short* __restrict__ qkT, unsigned short* __restrict__ vT,
    float* __restrict__ normsq) {
  __shared__ __align__(16) unsigned short lds[17408];  // As[128][64]@0, Bs@8192; bounce [128][136]
  int bj = blockIdx.x;                        // 0..17
  int bm = blockIdx.y;                        // 0..255
  int m0 = bm * 128, j0 = bj * 128;
  int tid = threadIdx.x;
  int wid = tid >> 6, lane = tid & 63;
  int wm = wid >> 1, wn = wid & 1;
  int quad = lane >> 4, l16 = lane & 15;
  int srow = lane >> 3, sch = lane & 7;       // staging: 8 rows x 8 chunks per instr
  int cmem = sch ^ srow;                      // swizzled chunk to fetch

  f32x4 acc[4][4];
  f32x4 z = {0.f, 0.f, 0.f, 0.f};
#pragma unroll
  for (int i = 0; i < 4; i++)
#pragma unroll
    for (int j = 0; j < 4; j++) acc[i][j] = z;

  const unsigned short* Ab = A + (size_t)m0 * 768;
  const unsigned short* Bb = Bt + (size_t)j0 * 768;

  for (int k0 = 0; k0 < 768; k0 += 64) {
#pragma unroll
    for (int i = 0; i < 4; i++) {
      int ig = wid * 4 + i;                   // 0..15, 8 rows each
      int row = ig * 8 + srow;
      gload16(Ab + (size_t)row * 768 + k0 + cmem * 8, &lds[ig * 512]);
      gload16(Bb + (size_t)row * 768 + k0 + cmem * 8, &lds[8192 + ig * 512]);
    }
    __syncthreads();
#pragma unroll
    for (int kk = 0; kk < 2; kk++) {
      int cs = ((kk * 4 + quad) ^ (l16 & 7)) * 8;
      bf16x8 af[4], bfr[4];
#pragma unroll
      for (int mi = 0; mi < 4; mi++)
        af[mi] = *(const bf16x8*)&lds[(wm * 64 + mi * 16 + l16) * 64 + cs];
#pragma unroll
      for (int ni = 0; ni < 4; ni++)
        bfr[ni] = *(const bf16x8*)&lds[8192 + (wn * 64 + ni * 16 + l16) * 64 + cs];
#pragma unroll
      for (int mi = 0; mi < 4; mi++)
#pragma unroll
        for (int ni = 0; ni < 4; ni++)
          acc[mi][ni] = __builtin_amdgcn_mfma_f32_16x16x32_bf16(af[mi], bfr[ni], acc[mi][ni], 0, 0, 0);
    }
    __syncthreads();
  }

  int s = bj / 6;                  // 0=q,1=k,2=v
  int b = bm >> 5;
  int n0 = m0 & 4095;
  bool isv = (s == 2);

  // fused norm^2 accumulation for q/k (fp32, pre-rounding)
  if (!isv) {
#pragma unroll
    for (int ni = 0; ni < 4; ni++) {
      float ss = 0.f;
#pragma unroll
      for (int mi = 0; mi < 4; mi++)
#pragma unroll
        for (int r = 0; r < 4; r++) ss += acc[mi][ni][r] * acc[mi][ni][r];
      ss += __shfl_down(ss, 32, 64);
      ss += __shfl_down(ss, 16, 64);
      if (lane < 16) {
        int cc = wn * 64 + ni * 16 + l16;
        int local = j0 + cc - s * 768;
        int hh = local / 96, d = local - hh * 96;
        atomicAdd(&normsq[s * 6144 + (b * 8 + hh) * 96 + d], ss);
      }
    }
  }

  // bounce (padded stride 136 -> no bank conflicts)
#pragma unroll
  for (int mi = 0; mi < 4; mi++)
#pragma unroll
    for (int ni = 0; ni < 4; ni++)
#pragma unroll
      for (int r = 0; r < 4; r++) {
        int m = wm * 64 + mi * 16 + quad * 4 + r;
        int cc = wn * 64 + ni * 16 + l16;
        unsigned short v = f2b(acc[mi][ni][r]);
        lds[isv ? (m * 136 + cc) : (cc * 136 + m)] = v;
      }
  __syncthreads();
  if (!isv) {
#pragma unroll
    for (int it = 0; it < 8; it++) {
      int id = tid + it * 256;
      int jr = id >> 4, mc = id & 15;
      int j = j0 + jr;
      int hh = (j - s * 768) / 96;
      int d = j - s * 768 - hh * 96;
      size_t off = ((size_t)(s * 64 + b * 8 + hh) * 96 + d) * 4096 + n0 + mc * 8;
      *(uint4*)&qkT[off] = *(const uint4*)&lds[jr * 136 + mc * 8];
    }
  } else {
#pragma unroll
    for (int it = 0; it < 8; it++) {
      int id = tid + it * 256;
      int mr = id >> 4, ch = id & 15;
      int cp = (j0 - 1536) + ch * 8;
      int hh = cp / 96, e = cp - hh * 96;
      size_t off = ((size_t)(b * 8 + hh) * 4096 + (n0 + mr)) * 96 + e;
      *(uint4*)&vT[off] = *(const uint4*)&lds[mr * 136 + ch * 8];
    }
  }
}

// ---------------- split-K S = q @ k^T ----------------
__global__ __launch_bounds__(256, 2) void attn_s(const unsigned short* __restrict__ qkT,
                                                 float* __restrict__ S) {
  __shared__ __align__(16) unsigned short lds[12288];  // qs[96][64]@0, ks@6144 (swizzled)
  int blk = blockIdx.x;
  int bh = blk >> 3, ks = blk & 7;
  const unsigned short* qb = qkT + (size_t)bh * 96 * 4096;
  const unsigned short* kb = qkT + (size_t)(64 + bh) * 96 * 4096;
  int tid = threadIdx.x, wid = tid >> 6, lane = tid & 63;
  int wm = wid >> 1, wn = wid & 1, quad = lane >> 4, l16 = lane & 15;
  int srow = lane >> 3, sch = lane & 7;
  int cmem = sch ^ srow;
  f32x4 acc[3][3];
  f32x4 z = {0.f, 0.f, 0.f, 0.f};
#pragma unroll
  for (int i = 0; i < 3; i++)
#pragma unroll
    for (int j = 0; j < 3; j++) acc[i][j] = z;

  for (int k0 = ks * 512; k0 < ks * 512 + 512; k0 += 64) {
#pragma unroll
    for (int i = 0; i < 3; i++) {
      int ig = wid * 3 + i;                  // 0..11, 8 rows each
      int row = ig * 8 + srow;
      gload16(qb + (size_t)row * 4096 + k0 + cmem * 8, &lds[ig * 512]);
      gload16(kb + (size_t)row * 4096 + k0 + cmem * 8, &lds[6144 + ig * 512]);
    }
    __syncthreads();
#pragma unroll
    for (int kk = 0; kk < 2; kk++) {
      int cs = ((kk * 4 + quad) ^ (l16 & 7)) * 8;
      bf16x8 af[3], bfr[3];
#pragma unroll
      for (int mi = 0; mi < 3; mi++)
        af[mi] = *(const bf16x8*)&lds[(wm * 48 + mi * 16 + l16) * 64 + cs];
#pragma unroll
      for (int ni = 0; ni < 3; ni++)
        bfr[ni] = *(const bf16x8*)&lds[6144 + (wn * 48 + ni * 16 + l16) * 64 + cs];
#pragma unroll
      for (int mi = 0; mi < 3; mi++)
#pragma unroll
        for (int ni = 0; ni < 3; ni++)
          acc[mi][ni] = __builtin_amdgcn_mfma_f32_16x16x32_bf16(af[mi], bfr[ni], acc[mi][ni], 0, 0, 0);
    }
    __syncthreads();
  }
  float* Sb = S + (size_t)bh * 9216;
#pragma unroll
  for (int mi = 0; mi < 3; mi++)
#pragma unroll
    for (int ni = 0; ni < 3; ni++)
#pragma unroll
      for (int r = 0; r < 4; r++)
        atomicAdd(&Sb[(wm * 48 + mi * 16 + quad * 4 + r) * 96 + wn * 48 + ni * 16 + l16],
                  acc[mi][ni][r]);
}

// ---------------- softmax + out = attn @ v ----------------
__global__ __launch_bounds__(256, 2) void attn_v(
    const float* __restrict__ S, const float* __restrict__ normsq,
    const float* __restrict__ temp, const unsigned short* __restrict__ vT,
    unsigned short* __restrict__ U) {
  // attn [96][104]@0 (9984), vs [128][13 chunks][8]@9984 (13312), ik floats @23296
  __shared__ __align__(16) unsigned short lds[23488];
  float* ik = (float*)&lds[23296];
  int blk = blockIdx.x;
  int bh = blk >> 5, nc = blk & 31;
  int b = bh >> 3, h = bh & 7;
  int n0 = nc * 128;
  int tid = threadIdx.x, wid = tid >> 6, lane = tid & 63;
  int wm = wid >> 1, wn = wid & 1, quad = lane >> 4, l16 = lane & 15;

  // stage v chunk [128 n][96 e] -> [row][13 chunks] (13*16B = 208B row, 2-way banks)
  const unsigned short* vb = vT + (size_t)bh * 4096 * 96 + (size_t)n0 * 96;
#pragma unroll
  for (int i = 0; i < 7; i++) {
    int ig = wid + i * 4;                   // 0..27
    if (ig < 26) {
      int id = ig * 64 + lane;              // slot = row*13 + chunk
      int row = id / 13;
      int ch = id - row * 13;
      if (ch > 11) ch = 11;                 // pad slot: load harmless dup
      gload16(vb + (size_t)row * 96 + ch * 8, &lds[9984 + ig * 512]);
    }
  }

  if (tid < 96)
    ik[tid] = 1.0f / fmaxf(sqrtf(normsq[6144 + bh * 96 + tid]), 1e-12f);
  __syncthreads();

  if (tid < 96) {
    int d = tid;
    const float* Srow = S + (size_t)bh * 9216 + d * 96;
    float iq = (1.0f / fmaxf(sqrtf(normsq[bh * 96 + d]), 1e-12f)) * temp[h];
    float mx = -1e30f;
    for (int e = 0; e < 96; e++) mx = fmaxf(mx, Srow[e] * iq * ik[e]);
    float sum = 0.f;
    for (int e = 0; e < 96; e++) sum += __expf(Srow[e] * iq * ik[e] - mx);
    float inv = 1.0f / sum;
    for (int e = 0; e < 96; e++)
      lds[d * 104 + e] = f2b(__expf(Srow[e] * iq * ik[e] - mx) * inv);
  }
  __syncthreads();

  f32x4 acc[3][4];
  f32x4 z = {0.f, 0.f, 0.f, 0.f};
#pragma unroll
  for (int i = 0; i < 3; i++)
#pragma unroll
    for (int j = 0; j < 4; j++) acc[i][j] = z;
#pragma unroll
  for (int et = 0; et < 3; et++) {
    bf16x8 af[3], bfr[4];
#pragma unroll
    for (int mi = 0; mi < 3; mi++)
      af[mi] = *(const bf16x8*)&lds[(wm * 48 + mi * 16 + l16) * 104 + (et * 4 + quad) * 8];
#pragma unroll
    for (int ni = 0; ni < 4; ni++)
      bfr[ni] = *(const bf16x8*)&lds[9984 + (wn * 64 + ni * 16 + l16) * 104 + (et * 4 + quad) * 8];
#pragma unroll
    for (int mi = 0; mi < 3; mi++)
#pragma unroll
      for (int ni = 0; ni < 4; ni++)
        acc[mi][ni] = __builtin_amdgcn_mfma_f32_16x16x32_bf16(af[mi], bfr[ni], acc[mi][ni], 0, 0, 0);
  }
  __syncthreads();

  // bounce [128 n][104] then coalesced U writes
#pragma unroll
  for (int mi = 0; mi < 3; mi++)
#pragma unroll
    for (int ni = 0; ni < 4; ni++)
#pragma unroll
      for (int r = 0; r < 4; r++) {
        int d = wm * 48 + mi * 16 + quad * 4 + r;
        int n = wn * 64 + ni * 16 + l16;
        lds[n * 104 + d] = f2b(acc[mi][ni][r]);
      }
  __syncthreads();
#pragma unroll
  for (int it = 0; it < 6; it++) {
    int id = tid + it * 256;                // 128 n x 12 chunks
    int nr = id / 12, ch = id - nr * 12;
    *(uint4*)&U[((size_t)(b * 4096 + n0 + nr)) * 768 + h * 96 + ch * 8] =
        *(const uint4*)&lds[nr * 104 + ch * 8];
  }
}

// ---------------- GEMM3: y = U @ Wproj + bproj ----------------
__global__ __launch_bounds__(256, 2) void gemm_out(
    const unsigned short* __restrict__ A, const unsigned short* __restrict__ Bt,
    const float* __restrict__ bias, float* __restrict__ out) {
  __shared__ __align__(16) unsigned short lds[16384];
  int bj = blockIdx.x;                      // 0..5
  int bm = blockIdx.y;                      // 0..255
  int m0 = bm * 128, j0 = bj * 128;
  int tid = threadIdx.x;
  int wid = tid >> 6, lane = tid & 63;
  int wm = wid >> 1, wn = wid & 1;
  int quad = lane >> 4, l16 = lane & 15;
  int srow = lane >> 3, sch = lane & 7;
  int cmem = sch ^ srow;

  f32x4 acc[4][4];
  f32x4 z = {0.f, 0.f, 0.f, 0.f};
#pragma unroll
  for (int i = 0; i < 4; i++)
#pragma unroll
    for (int j = 0; j < 4; j++) acc[i][j] = z;

  const unsigned short* Ab = A + (size_t)m0 * 768;
  const unsigned short* Bb = Bt + (size_t)j0 * 768;

  for (int k0 = 0; k0 < 768; k0 += 64) {
#pragma unroll
    for (int i = 0; i < 4; i++) {
      int ig = wid * 4 + i;
      int row = ig * 8 + srow;
      gload16(Ab + (size_t)row * 768 + k0 + cmem * 8, &lds[ig * 512]);
      gload16(Bb + (size_t)row * 768 + k0 + cmem * 8, &lds[8192 + ig * 512]);
    }
    __syncthreads();
#pragma unroll
    for (int kk = 0; kk < 2; kk++) {
      int cs = ((kk * 4 + quad) ^ (l16 & 7)) * 8;
      bf16x8 af[4], bfr[4];
#pragma unroll
      for (int mi = 0; mi < 4; mi++)
        af[mi] = *(const bf16x8*)&lds[(wm * 64 + mi * 16 + l16) * 64 + cs];
#pragma unroll
      for (int ni = 0; ni < 4; ni++)
        bfr[ni] = *(const bf16x8*)&lds[8192 + (wn * 64 + ni * 16 + l16) * 64 + cs];
#pragma unroll
      for (int mi = 0; mi < 4; mi++)
#pragma unroll
        for (int ni = 0; ni < 4; ni++)
          acc[mi][ni] = __builtin_amdgcn_mfma_f32_16x16x32_bf16(af[mi], bfr[ni], acc[mi][ni], 0, 0, 0);
    }
    __syncthreads();
  }
#pragma unroll
  for (int ni = 0; ni < 4; ni++) {
    int ccol = j0 + wn * 64 + ni * 16 + l16;
    float bv = bias[ccol];
#pragma unroll
    for (int mi = 0; mi < 4; mi++)
#pragma unroll
      for (int r = 0; r < 4; r++)
        out[(size_t)(m0 + wm * 64 + mi * 16 + quad * 4 + r) * 768 + ccol] = acc[mi][ni][r] + bv;
  }
}

// ---------------- host ----------------
extern "C" void kernel_launch(void* const* d_in, const int* in_sizes, int n_in,
                              void* d_out, int out_size, void* d_ws, size_t ws_size,
                              hipStream_t stream) {
  const float* x = (const float*)d_in[0];
  const float* Wqkv = (const float*)d_in[1];
  const float* temp = (const float*)d_in[2];
  const float* Wproj = (const float*)d_in[3];
  const float* bproj = (const float*)d_in[4];
  float* out = (float*)d_out;
  char* ws = (char*)d_ws;

  unsigned short* xb     = (unsigned short*)(ws);                 // 50331648 B
  unsigned short* WqkvT  = (unsigned short*)(ws + 50331648);      // 3538944
  unsigned short* WprojT = (unsigned short*)(ws + 53870592);      // 1179648
  unsigned short* qkT    = (unsigned short*)(ws + 55050240);      // 100663296
  unsigned short* vT     = (unsigned short*)(ws + 155713536);     // 50331648
  unsigned short* U      = (unsigned short*)(ws + 206045184);     // 50331648
  float* S               = (float*)(ws + 256376832);              // 2359296
  float* normsq          = (float*)(ws + 258736128);              // 49152 (contiguous after S)

  cvt_bf16<<<dim3(4096), dim3(256), 0, stream>>>(x, xb, 25165824 / 4, S, 150528);
  cvt_transpose<<<dim3(72, 24), dim3(256), 0, stream>>>(Wqkv, WqkvT, 768, 2304);
  cvt_transpose<<<dim3(24, 24), dim3(256), 0, stream>>>(Wproj, WprojT, 768, 768);
  gemm_qkv<<<dim3(18, 256), dim3(256), 0, stream>>>(xb, WqkvT, qkT, vT, normsq);
  attn_s<<<dim3(512), dim3(256), 0, stream>>>(qkT, S);
  attn_v<<<dim3(2048), dim3(256), 0, stream>>>(S, normsq, temp, vT, U);
  gemm_out<<<dim3(6, 256), dim3(256), 0, stream>>>(U, WprojT, bproj, out);
}